// Round 7
// baseline (488.367 us; speedup 1.0000x reference)
//
#include <hip/hip_runtime.h>
#include <hip/hip_bf16.h>
#include <stdint.h>

#define M_DIM 8192
#define K_DIM 4096
#define N_DIM 4096

typedef __attribute__((ext_vector_type(8))) short short8;
typedef __attribute__((ext_vector_type(16))) float floatx16;

// ---------------- fused per-row abs-mean scale + ternary quantize ----------------
__global__ void fused_scale_quant(const float* __restrict__ w, float* __restrict__ scales,
                                  __hip_bfloat16* __restrict__ qb) {
    int row = blockIdx.x;
    const float4* wr = (const float4*)(w + (size_t)row * K_DIM);
    float4 v[4];
    double s = 0.0;
    #pragma unroll
    for (int i = 0; i < 4; i++) {
        v[i] = wr[threadIdx.x + 256 * i];
        s += (double)fabsf(v[i].x) + (double)fabsf(v[i].y) +
             (double)fabsf(v[i].z) + (double)fabsf(v[i].w);
    }
    #pragma unroll
    for (int off = 32; off > 0; off >>= 1) s += __shfl_down(s, off);
    __shared__ double partial[4];
    __shared__ float s_scale;
    int wave = threadIdx.x >> 6;
    if ((threadIdx.x & 63) == 0) partial[wave] = s;
    __syncthreads();
    if (threadIdx.x == 0) {
        double t = partial[0] + partial[1] + partial[2] + partial[3];
        float m = (float)(t / (double)K_DIM);
        m = fmaxf(m, 1e-5f);
        scales[row] = m;
        s_scale = m;
    }
    __syncthreads();
    float sc = s_scale;
    __hip_bfloat16* qr = qb + (size_t)row * K_DIM;
    #pragma unroll
    for (int i = 0; i < 4; i++) {
        float q0 = fminf(fmaxf(rintf(v[i].x / sc), -1.f), 1.f);
        float q1 = fminf(fmaxf(rintf(v[i].y / sc), -1.f), 1.f);
        float q2 = fminf(fmaxf(rintf(v[i].z / sc), -1.f), 1.f);
        float q3 = fminf(fmaxf(rintf(v[i].w / sc), -1.f), 1.f);
        __hip_bfloat16 o[4] = {__float2bfloat16(q0), __float2bfloat16(q1),
                               __float2bfloat16(q2), __float2bfloat16(q3)};
        *(uint2*)(qr + 4 * (threadIdx.x + 256 * i)) = *(uint2*)o;
    }
}

// ---------------- x fp32 -> bf16 ----------------
__global__ void xconv_kernel(const float* __restrict__ x, __hip_bfloat16* __restrict__ xb) {
    size_t v = (size_t)blockIdx.x * blockDim.x + threadIdx.x;
    float4 a = ((const float4*)x)[2 * v];
    float4 b = ((const float4*)x)[2 * v + 1];
    __hip_bfloat16 o[8] = {__float2bfloat16(a.x), __float2bfloat16(a.y),
                           __float2bfloat16(a.z), __float2bfloat16(a.w),
                           __float2bfloat16(b.x), __float2bfloat16(b.y),
                           __float2bfloat16(b.z), __float2bfloat16(b.w)};
    *(uint4*)(xb + 8 * v) = *(uint4*)o;
}

// ---------------- 256x256 bf16 MFMA GEMM (32x32x16, 1-barrier-per-tile pipeline) ----------------
// v6: within a tile, all ds_reads target the stable CURRENT buffer and all DMA
// writes target the RETIRED buffer -> v5's per-phase barriers were pure overhead
// and serialized read-drain with MFMA (MfmaUtil 46%, 25.7M conflict cycles on
// the critical path). v6 keeps ONE {lgkmcnt(0); vmcnt(0); barrier} per tile,
// double-buffers fragments (set0/set1, +24 VGPR only at 32x32), and issues each
// K-step's reads one MFMA-cluster ahead as plain C loads so the compiler's
// counted lgkm waits overlap read drain (and its conflicts) under MFMA.
// Hazard graph: stage->nbuf is >=1 {lgkm0->barrier} after nbuf's last read on
// all waves; per-tile vmcnt(0)+barrier certifies next tile resident; the
// post-barrier RD(nbuf,k0) keeps the boundary cluster fed.
__device__ __forceinline__ void load16(const void* g, void* l) {
    __builtin_amdgcn_global_load_lds((const __attribute__((address_space(1))) uint32_t*)g,
                                     (__attribute__((address_space(3))) uint32_t*)l, 16, 0, 0);
}

#define BARRIER() do { asm volatile("" ::: "memory"); __builtin_amdgcn_s_barrier(); asm volatile("" ::: "memory"); } while (0)
#define VM0 asm volatile("s_waitcnt vmcnt(0)" ::: "memory")
#define LGKM0 asm volatile("s_waitcnt lgkmcnt(0)" ::: "memory")

// LDS map (128 KiB): buf d at d*65536; A0 at +0, A1 at +16384, B0 at +32768, B1 at +49152.
// Each half: 128 rows x 64 bf16 (128B/row = 8 chunks); chunk c of row r at slot
// r*8 + (c ^ (r&7)). global_load_lds dest is linear (tid*16); the XOR swizzle is
// applied to the GLOBAL source (inverse) and the ds_read address (forward) — rule #21.

#define STAGE_A0(OFF, t) do { load16(gA00 + (t)*64, ldsw + (OFF));          load16(gA01 + (t)*64, ldsw + (OFF) + 8192); } while (0)
#define STAGE_A1(OFF, t) do { load16(gA10 + (t)*64, ldsw + (OFF) + 16384);  load16(gA11 + (t)*64, ldsw + (OFF) + 24576); } while (0)
#define STAGE_B0(OFF, t) do { load16(gB00 + (t)*64, ldsw + (OFF) + 32768);  load16(gB01 + (t)*64, ldsw + (OFF) + 40960); } while (0)
#define STAGE_B1(OFF, t) do { load16(gB10 + (t)*64, ldsw + (OFF) + 49152);  load16(gB11 + (t)*64, ldsw + (OFF) + 57344); } while (0)

// Per K-step kk: 4 A-frags (M rows wr*64 + (mt&1)*32 + l31, half mt>>1) and
// 2 B-frags (N rows wc*32 + l31, half nt). Lane's 8 bf16 at k-chunk
// c = kk*2 + (lane>>5), swizzled slot = c ^ (lane&7) (row&7 == lane&7).
#define RD6(DA, DB, BUF, KO) do { \
    DA[0] = *(const short8*)(lds + (BUF) +     0 + aRow + (KO)); \
    DA[1] = *(const short8*)(lds + (BUF) +  4096 + aRow + (KO)); \
    DA[2] = *(const short8*)(lds + (BUF) + 16384 + aRow + (KO)); \
    DA[3] = *(const short8*)(lds + (BUF) + 20480 + aRow + (KO)); \
    DB[0] = *(const short8*)(lds + (BUF) + 32768 + bRow + (KO)); \
    DB[1] = *(const short8*)(lds + (BUF) + 49152 + bRow + (KO)); \
} while (0)

#define MFMA8(AF, BF) do { \
    __builtin_amdgcn_s_setprio(1); \
    _Pragma("unroll") for (int mt_ = 0; mt_ < 4; ++mt_) \
    _Pragma("unroll") for (int nt_ = 0; nt_ < 2; ++nt_) \
        acc[mt_][nt_] = __builtin_amdgcn_mfma_f32_32x32x16_bf16(AF[mt_], BF[nt_], acc[mt_][nt_], 0, 0, 0); \
    __builtin_amdgcn_s_setprio(0); \
} while (0)

__global__ __launch_bounds__(512, 1) void gemm_kernel(const __hip_bfloat16* __restrict__ xb,
                                                      const __hip_bfloat16* __restrict__ qb,
                                                      const float* __restrict__ scales,
                                                      float* __restrict__ out) {
    __shared__ __align__(16) char smem[131072];
    char* lds = smem;
    const int tid = threadIdx.x;
    const int lane = tid & 63;
    const int wave = tid >> 6;
    const int wr = wave >> 2;   // 2 wave-rows (M)
    const int wc = wave & 3;    // 4 wave-cols (N)

    // XCD swizzle: 512 wgs, 8 XCDs, 64 contiguous per XCD (bijective, 512%8==0)
    int bid = blockIdx.x;
    int swz = (bid & 7) * 64 + (bid >> 3);
    const int m0 = (swz >> 4) * 256;
    const int n0 = (swz & 15) * 256;

    // staging source (inverse-swizzled): thread covers chunks tid and tid+512 of each half
    const int r0 = tid >> 3,         c0 = (tid & 7) ^ (r0 & 7);
    const int r1 = (tid + 512) >> 3, c1 = ((tid + 512) & 7) ^ (r1 & 7);
    const __hip_bfloat16* gA00 = xb + (size_t)(m0 + r0) * K_DIM + c0 * 8;
    const __hip_bfloat16* gA01 = xb + (size_t)(m0 + r1) * K_DIM + c1 * 8;
    const __hip_bfloat16* gA10 = gA00 + (size_t)128 * K_DIM;
    const __hip_bfloat16* gA11 = gA01 + (size_t)128 * K_DIM;
    const __hip_bfloat16* gB00 = qb + (size_t)(n0 + r0) * K_DIM + c0 * 8;
    const __hip_bfloat16* gB01 = qb + (size_t)(n0 + r1) * K_DIM + c1 * 8;
    const __hip_bfloat16* gB10 = gB00 + (size_t)128 * K_DIM;
    const __hip_bfloat16* gB11 = gB01 + (size_t)128 * K_DIM;
    char* ldsw = lds + tid * 16;

    // per-lane read bases: A rows = wr*64 + (lane&31), B rows = wc*32 + (lane&31)
    const int l31 = lane & 31, l7 = lane & 7, lq5 = lane >> 5;
    const int aRow = (wr * 64 + l31) * 128;
    const int bRow = (wc * 32 + l31) * 128;
    // k-chunk offsets per K-step kk: ((kk*2 + lq5) ^ l7) * 16
    const int k0 = ((0 + lq5) ^ l7) * 16;
    const int k1 = ((2 + lq5) ^ l7) * 16;
    const int k2 = ((4 + lq5) ^ l7) * 16;
    const int k3 = ((6 + lq5) ^ l7) * 16;

    floatx16 acc[4][2] = {};          // [mt][nt] — 128 acc regs
    short8 aF[4], bF[2];              // fragment set 0 (24 VGPR)
    short8 aG[4], bG[2];              // fragment set 1 (24 VGPR)

    // prologue: stage tile 0 into buf0, drain, certify, pre-read k0
    STAGE_A0(0, 0); STAGE_B0(0, 0); STAGE_A1(0, 0); STAGE_B1(0, 0);
    VM0;
    BARRIER();
    RD6(aF, bF, 0, k0);

    // main: tiles 0..62; tile t computes from buf (t&1), stages t+1 into the
    // retired buffer, one sync point per tile.
    #pragma unroll 1
    for (int it = 0; it < 63; ++it) {
        const int buf = (it & 1) << 16;
        const int nbuf = buf ^ 65536;
        RD6(aG, bG, buf, k1);
        STAGE_A0(nbuf, it + 1); STAGE_B0(nbuf, it + 1); STAGE_A1(nbuf, it + 1);
        MFMA8(aF, bF);                       // k0
        RD6(aF, bF, buf, k2);
        STAGE_B1(nbuf, it + 1);
        MFMA8(aG, bG);                       // k1
        RD6(aG, bG, buf, k3);
        MFMA8(aF, bF);                       // k2
        LGKM0;                               // all reads of buf drained (overwrite safety)
        VM0;                                 // tile t+1 staging complete (this wave)
        BARRIER();                           // ... for all waves
        RD6(aF, bF, nbuf, k0);               // next tile k0 (certified resident)
        MFMA8(aG, bG);                       // k3
    }
    // tile 63 (buf1): staged during it=62, vmcnt already drained there
    RD6(aG, bG, 65536, k1); MFMA8(aF, bF);
    RD6(aF, bF, 65536, k2); MFMA8(aG, bG);
    RD6(aG, bG, 65536, k3); MFMA8(aF, bF);
    LGKM0;
    BARRIER();                               // all reads done before LDS reuse below
    MFMA8(aG, bG);

    // ---- epilogue: per-wave LDS transpose (stride 68), scaled coalesced f32 stores ----
    // 32x32 C/D layout (m74/m101): col = lane&31, row = (reg&3) + 8*(reg>>2) + 4*(lane>>5).
    float* epi = (float*)(lds + wave * 8704);   // 32 rows x stride 68 floats
    const int cn = lane & 15, qd = lane >> 4;
    float scl[2];
    #pragma unroll
    for (int nt = 0; nt < 2; ++nt) scl[nt] = scales[n0 + nt * 128 + wc * 32 + l31];

    // local col L=0..63 <-> global col n0 + wc*32 + nt*128 (two 128B islands per row)
    const int colb = n0 + wc * 32 + ((cn >= 8) ? (128 + (cn - 8) * 4) : cn * 4);

    #pragma unroll
    for (int mt = 0; mt < 4; ++mt) {
        // stage 32x64 (scaled) into LDS
        #pragma unroll
        for (int nt = 0; nt < 2; ++nt)
            #pragma unroll
            for (int r = 0; r < 16; ++r) {
                int row = (r & 3) + 8 * (r >> 2) + 4 * lq5;
                epi[row * 68 + nt * 32 + l31] = acc[mt][nt][r] * scl[nt];
            }
        const int rowb = m0 + (mt >> 1) * 128 + wr * 64 + (mt & 1) * 32;
        // read back coalesced: 8 passes of 4 rows x 64 cols (256B contiguous per row)
        #pragma unroll
        for (int p = 0; p < 8; ++p) {
            float4 vv = *(const float4*)&epi[(p * 4 + qd) * 68 + cn * 4];
            *(float4*)&out[(size_t)(rowb + p * 4 + qd) * N_DIM + colb] = vv;
        }
    }
}

extern "C" void kernel_launch(void* const* d_in, const int* in_sizes, int n_in,
                              void* d_out, int out_size, void* d_ws, size_t ws_size,
                              hipStream_t stream) {
    const float* x = (const float*)d_in[0];
    const float* w = (const float*)d_in[1];
    float* out = (float*)d_out;

    char* ws = (char*)d_ws;
    __hip_bfloat16* xb = (__hip_bfloat16*)ws;
    __hip_bfloat16* qb = (__hip_bfloat16*)(ws + (size_t)M_DIM * K_DIM * 2);
    float* scales = (float*)(ws + (size_t)M_DIM * K_DIM * 2 + (size_t)N_DIM * K_DIM * 2);

    fused_scale_quant<<<N_DIM, 256, 0, stream>>>(w, scales, qb);
    xconv_kernel<<<(M_DIM * K_DIM / 8) / 256, 256, 0, stream>>>(x, xb);
    gemm_kernel<<<(M_DIM / 256) * (N_DIM / 256), 512, 0, stream>>>(xb, qb, scales, out);
}